// Round 1
// baseline (626.827 us; speedup 1.0000x reference)
//
#include <hip/hip_runtime.h>
#include <math.h>

#define BB 16
#define CC 256
#define NN 4096
#define KK 8

// ws layout (float offsets)
#define OFF_S      ((size_t)0)          // [2][16][8]
#define OFF_WX     ((size_t)256)        // [2][16][8][256]
#define OFF_G      ((size_t)65792)      // [2][16][64]
#define OFF_CS     ((size_t)67840)      // [4 conv][2][256]  (sum, sumsq)
#define OFF_MS     ((size_t)69888)      // [2 dir][2][256]
#define OFF_CK     ((size_t)70912)      // [2][8]  sum_c anchor^2 * inv_s2
#define ACC_FLOATS ((size_t)70928)
#define OFF_ASSIGN ((size_t)70928)      // [2][16][8][4096]
#define OFF_GRAPH  ((size_t)1119504)    // [2][16][2048]  (nodes layout k*256+c; [C][K] view = flat[c*8+k])
#define OFF_CLP    ((size_t)1185040)    // float2 [2][256][8]: per (c,k): (inv_s2, -2*anchor*inv_s2)
#define OFF_WT     ((size_t)1193232)    // [6][256][256] transposed conv weights
#define OFF_Y      ((size_t)1586448)    // [4 conv][16][256][8] raw conv outputs
#define OFF_CE     ((size_t)1717520)    // [2 dir][16][256][8]
#define WS_FLOATS  ((size_t)1783056)

// ---------------- K0: weight transposes + cluster params ----------------
__global__ __launch_bounds__(256) void k0_prep(
    const float* __restrict__ w0, const float* __restrict__ w1,
    const float* __restrict__ w2, const float* __restrict__ w3,
    const float* __restrict__ w4, const float* __restrict__ w5,
    const float* __restrict__ anch_r, const float* __restrict__ sig_r,
    const float* __restrict__ anch_t, const float* __restrict__ sig_t,
    float* __restrict__ ws)
{
    int bid = blockIdx.x, tid = threadIdx.x;
    if (bid < 1536) {
        int widx = bid >> 8;
        int e = ((bid & 255) << 8) + tid;     // 0..65535
        int o = e >> 8, i = e & 255;
        const float* W = widx == 0 ? w0 : widx == 1 ? w1 : widx == 2 ? w2 :
                         widx == 3 ? w3 : widx == 4 ? w4 : w5;
        ws[OFF_WT + (size_t)widx * 65536 + (size_t)i * 256 + o] = W[o * 256 + i];
    } else {
        int pid = ((bid - 1536) << 8) + tid;  // 0..4095
        int M = pid >> 11, j = pid & 2047;
        int k = j >> 8, c = j & 255;
        const float* sg = M ? sig_t : sig_r;
        const float* an = M ? anch_t : anch_r;
        float s = 1.f / (1.f + expf(-sg[j]));
        float is2 = 1.f / (s * s);
        float a = an[j];
        float2* c2 = (float2*)(ws + OFF_CLP);
        // interleaved [c][k] layout -> k1 reads 4x float4 per channel
        c2[(size_t)M * 2048 + (size_t)c * 8 + k] = make_float2(is2, -2.f * a * is2);
        // per-cluster constant term of the distance (k-dependent -> NOT softmax-invariant)
        atomicAdd(&ws[OFF_CK + (size_t)M * 8 + k], a * a * is2);
    }
}

// ---------------- K1: gate, assign, wx/s/G accumulation ----------------
// LDS cut from 60.5KB -> 44.3KB (pr_s dropped; coefficients come from L1 as
// wave-uniform float4 loads) -> 3 blocks/CU instead of 2.
// out is NOT written here anymore (k6 recomputes x = gate*X); only the gate
// scalar is stashed in out's channel-0 plane (overwritten later by k6).
__global__ __launch_bounds__(256) void k1_gate_assign(
    const float* __restrict__ rgb, const float* __restrict__ t,
    const float* __restrict__ edger, const float* __restrict__ edget,
    const float* __restrict__ pred_w, const float* __restrict__ pred_b,
    float* __restrict__ out, float* __restrict__ ws)
{
    int tile = blockIdx.x;          // 0..63
    int b    = blockIdx.y;          // 0..15
    int M    = blockIdx.z;          // 0 rgb, 1 t
    int tid  = threadIdx.x;
    int tx = tid & 63, ty = tid >> 6;
    int n0 = tile * 64;

    const float* X = M ? t : rgb;
    const float* E = M ? edget : edger;

    __shared__ _Float16 xs[CC][66];
    __shared__ float qp[KK][4][64];
    __shared__ float gatep[4][64];
    __shared__ float gate_s[64];
    __shared__ float asg[KK][64];
    __shared__ float cks[KK];

    if (tid < KK) cks[tid] = ws[OFF_CK + (size_t)M * 8 + tid];

    // phase A: gate partial dot
    const float* Eb = E + ((size_t)b * CC) * NN + n0 + tx;
    float acc = 0.f;
#pragma unroll 4
    for (int c = ty * 64; c < ty * 64 + 64; ++c)
        acc += pred_w[c] * Eb[(size_t)c * NN];
    gatep[ty][tx] = acc;
    __syncthreads();
    if (tid < 64) {
        float g = gatep[0][tx] + gatep[1][tx] + gatep[2][tx] + gatep[3][tx] + pred_b[0];
        float sg = 1.f / (1.f + expf(-g));
        gate_s[tx] = sg;
        // stash gate in out channel-0 plane; k6 reads it before overwriting
        out[(((size_t)M * BB + b) * CC) * NN + n0 + tx] = sg;
    }
    __syncthreads();

    // phase B: x = gate*input, stage to LDS, partial q
    const float* Xb = X + ((size_t)b * CC) * NN + n0 + tx;
    const float4* prq = (const float4*)(ws + OFF_CLP) + (size_t)M * 1024; // [256][4] float4
    float gt = gate_s[tx];
    float qk[KK];
#pragma unroll
    for (int k = 0; k < KK; ++k) qk[k] = 0.f;
#pragma unroll 2
    for (int c = ty * 64; c < ty * 64 + 64; ++c) {
        float x = gt * Xb[(size_t)c * NN];
        xs[c][tx] = (_Float16)x;
        float xx = x * x;
        float4 p0 = prq[c * 4 + 0];   // k=0,1 : (is2, -2a*is2)
        float4 p1 = prq[c * 4 + 1];   // k=2,3
        float4 p2 = prq[c * 4 + 2];   // k=4,5
        float4 p3 = prq[c * 4 + 3];   // k=6,7
        qk[0] += xx * p0.x + x * p0.y;  qk[1] += xx * p0.z + x * p0.w;
        qk[2] += xx * p1.x + x * p1.y;  qk[3] += xx * p1.z + x * p1.w;
        qk[4] += xx * p2.x + x * p2.y;  qk[5] += xx * p2.z + x * p2.w;
        qk[6] += xx * p3.x + x * p3.y;  qk[7] += xx * p3.z + x * p3.w;
    }
#pragma unroll
    for (int k = 0; k < KK; ++k) qp[k][ty][tx] = qk[k];
    __syncthreads();

    // phase C: softmax over clusters (wave 0)
    float* assign_g = ws + OFF_ASSIGN + (((size_t)M * BB + b) * KK) * NN;
    if (tid < 64) {
        float q[KK], mx = -1e30f;
#pragma unroll
        for (int k = 0; k < KK; ++k) {
            q[k] = -0.5f * (qp[k][0][tx] + qp[k][1][tx] + qp[k][2][tx] + qp[k][3][tx] + cks[k]);
            mx = fmaxf(mx, q[k]);
        }
        float sm = 0.f;
#pragma unroll
        for (int k = 0; k < KK; ++k) { q[k] = expf(q[k] - mx); sm += q[k]; }
        float inv = 1.f / sm;
#pragma unroll
        for (int k = 0; k < KK; ++k) {
            float a = q[k] * inv;
            asg[k][tx] = a;
            assign_g[(size_t)k * NN + n0 + tx] = a;
        }
    }
    __syncthreads();

    // phase D: wx partial (matmul assign[8x64] @ x[64x256]) + s + G
    {
        int c = tid;
        float a0[KK];
#pragma unroll
        for (int k = 0; k < KK; ++k) a0[k] = 0.f;
#pragma unroll 4
        for (int j = 0; j < 64; ++j) {
            float xv = (float)xs[c][j];
#pragma unroll
            for (int k = 0; k < KK; ++k) a0[k] += asg[k][j] * xv;
        }
        float* wx_g = ws + OFF_WX + ((size_t)M * BB + b) * KK * CC;
#pragma unroll
        for (int k = 0; k < KK; ++k)
            atomicAdd(&wx_g[k * CC + c], a0[k]);
    }
    if (tid < 64) {
        int k1 = tid >> 3, k2 = tid & 7;
        float g = 0.f;
        for (int j = 0; j < 64; ++j) g += asg[k1][j] * asg[k2][j];
        atomicAdd(&ws[OFF_G + ((size_t)M * BB + b) * 64 + tid], g);
    } else if (tid < 72) {
        int k = tid - 64;
        float sv = 0.f;
        for (int j = 0; j < 64; ++j) sv += asg[k][j];
        atomicAdd(&ws[OFF_S + ((size_t)M * BB + b) * KK + k], sv);
    }
}

// ---------------- K2: nodes + double l2-normalize -> graph ----------------
__global__ __launch_bounds__(256) void k2_nodes(
    const float* __restrict__ anch_r, const float* __restrict__ sig_r,
    const float* __restrict__ anch_t, const float* __restrict__ sig_t,
    float* __restrict__ ws)
{
    int b = blockIdx.x & 15, M = blockIdx.x >> 4;
    int c = threadIdx.x;
    const float* an = M ? anch_t : anch_r;
    const float* sg = M ? sig_t : sig_r;
    const float* wx = ws + OFF_WX + ((size_t)M * BB + b) * KK * CC;
    const float* sp = ws + OFF_S + ((size_t)M * BB + b) * KK;
    float* gout = ws + OFF_GRAPH + ((size_t)M * BB + b) * 2048;

    __shared__ float nod[KK][CC];
    __shared__ float nrm[KK];
    __shared__ float gp[CC];
    __shared__ float gnrm;

    float node[KK];
#pragma unroll
    for (int k = 0; k < KK; ++k) {
        float s = sp[k];
        float sig = 1.f / (1.f + expf(-sg[k * CC + c]));
        float v = (wx[k * CC + c] - s * an[k * CC + c]) / sig / (s + 1e-9f);
        node[k] = v;
        nod[k][c] = v;
    }
    __syncthreads();
    if (c < KK) {
        float ss = 0.f;
        for (int i = 0; i < CC; ++i) ss += nod[c][i] * nod[c][i];
        nrm[c] = fmaxf(sqrtf(ss), 1e-12f);
    }
    __syncthreads();
    float gs = 0.f;
#pragma unroll
    for (int k = 0; k < KK; ++k) { node[k] /= nrm[k]; gs += node[k] * node[k]; }
    gp[c] = gs;
    __syncthreads();
    if (c == 0) {
        float ss = 0.f;
        for (int i = 0; i < CC; ++i) ss += gp[i];
        gnrm = fmaxf(sqrtf(ss), 1e-12f);
    }
    __syncthreads();
    float inv = 1.f / gnrm;
#pragma unroll
    for (int k = 0; k < KK; ++k)
        gout[k * CC + c] = node[k] * inv;   // nodes layout == flat; [C][K] view reads flat[c*8+k]
}

// ---------------- K3: four graph convs (raw y) + BN stats ----------------
__global__ __launch_bounds__(256) void k3_conv(float* __restrict__ ws)
{
    int conv = blockIdx.x >> 4, b = blockIdx.x & 15;
    int o = threadIdx.x;
    int M = conv >> 1;
    const float* gsrc = ws + OFF_GRAPH + ((size_t)M * BB + b) * 2048;
    const float* wt = ws + OFF_WT + (size_t)conv * 65536;
    __shared__ float gsh[2048];
    for (int i = o; i < 2048; i += 256) gsh[i] = gsrc[i];
    __syncthreads();
    float acc[KK];
#pragma unroll
    for (int k = 0; k < KK; ++k) acc[k] = 0.f;
    for (int i = 0; i < CC; ++i) {
        float w = wt[(size_t)i * 256 + o];
#pragma unroll
        for (int k = 0; k < KK; ++k) acc[k] += w * gsh[i * 8 + k];  // edge[i][k] = flat[i*8+k]
    }
    float* y = ws + OFF_Y + ((size_t)conv * BB + b) * 2048;
    float s1 = 0.f, s2 = 0.f;
#pragma unroll
    for (int k = 0; k < KK; ++k) { y[o * 8 + k] = acc[k]; s1 += acc[k]; s2 += acc[k] * acc[k]; }
    atomicAdd(&ws[OFF_CS + (size_t)conv * 512 + o], s1);
    atomicAdd(&ws[OFF_CS + (size_t)conv * 512 + 256 + o], s2);
}

// ---------------- K4: mutual correlation + cascade GCN + ce + final BN stats ----------------
__device__ __forceinline__ void gcn_layer(const float* __restrict__ Wg,
                                          float* xin, float* xout, float* am,
                                          float* sup, int o, bool do_relu)
{
    if (o < 64) {
        int k = o >> 3, l = o & 7;
        float s = 0.f;
        for (int i = 0; i < CC; ++i) s += xin[i * 9 + k] * xin[i * 9 + l];
        am[k * 9 + l] = s;
    }
    __syncthreads();
    if (o < 8) {
        float mx = -1e30f;
#pragma unroll
        for (int l = 0; l < 8; ++l) mx = fmaxf(mx, am[o * 9 + l]);
        float e[8], sm = 0.f;
#pragma unroll
        for (int l = 0; l < 8; ++l) { e[l] = expf(am[o * 9 + l] - mx); sm += e[l]; }
        float inv = 1.f / sm;
#pragma unroll
        for (int l = 0; l < 8; ++l) am[o * 9 + l] = e[l] * inv;
    }
    // sup[k][o] = sum_i xin[i][k] * Wg[i][o]   (independent of am)
    float sa[8];
#pragma unroll
    for (int k = 0; k < 8; ++k) sa[k] = 0.f;
    for (int i = 0; i < CC; ++i) {
        float w = Wg[(size_t)i * 256 + o];
#pragma unroll
        for (int k = 0; k < 8; ++k) sa[k] += xin[i * 9 + k] * w;
    }
#pragma unroll
    for (int k = 0; k < 8; ++k) sup[k * 256 + o] = sa[k];
    __syncthreads();
#pragma unroll
    for (int k = 0; k < 8; ++k) {
        float v = 0.f;
#pragma unroll
        for (int l = 0; l < 8; ++l) v += am[k * 9 + l] * sup[l * 256 + o];
        xout[o * 9 + k] = do_relu ? fmaxf(v, 0.f) : v;
    }
    __syncthreads();
}

__global__ __launch_bounds__(256) void k4_mutual(
    const float* __restrict__ rc1g, const float* __restrict__ rc1b,
    const float* __restrict__ rc2g, const float* __restrict__ rc2b,
    const float* __restrict__ tc1g, const float* __restrict__ tc1b,
    const float* __restrict__ tc2g, const float* __restrict__ tc2b,
    const float* __restrict__ t2rg1, const float* __restrict__ t2rg2,
    const float* __restrict__ r2tg1, const float* __restrict__ r2tg2,
    float* __restrict__ ws)
{
    int D = blockIdx.x >> 4, b = blockIdx.x & 15;
    int o = threadIdx.x;
    int M = D;                             // assign/graph modality of the receiving side
    int convR1 = D ? 0 : 2;                // r1 source conv
    int convR2 = D ? 1 : 3;
    const float* g1p = D ? rc1g : tc1g;  const float* b1p = D ? rc1b : tc1b;
    const float* g2p = D ? rc2g : tc2g;  const float* b2p = D ? rc2b : tc2b;
    const float* gcn1 = D ? r2tg1 : t2rg1;
    const float* gcn2 = D ? r2tg2 : t2rg2;
    const float* cwT = ws + OFF_WT + (size_t)(4 + D) * 65536;

    __shared__ float edge_s[CC * 9];
    __shared__ float r1_s[CC * 9];
    __shared__ float r2_s[CC * 9];
    __shared__ float x0[CC * 9];
    __shared__ float x1[CC * 9];
    __shared__ float sup[KK * CC];
    __shared__ float am[KK * 9];
    __shared__ float sS[KK];
    __shared__ float gS[64];

    if (o < 8)  sS[o] = ws[OFF_S + ((size_t)M * BB + b) * 8 + o];
    if (o < 64) gS[o] = ws[OFF_G + ((size_t)M * BB + b) * 64 + o];

    const float* egr = ws + OFF_GRAPH + ((size_t)M * BB + b) * 2048;
    const float* y1 = ws + OFF_Y + ((size_t)convR1 * BB + b) * 2048;
    const float* y2 = ws + OFF_Y + ((size_t)convR2 * BB + b) * 2048;
    float m1 = ws[OFF_CS + (size_t)convR1 * 512 + o] * (1.f / 128.f);
    float q1 = ws[OFF_CS + (size_t)convR1 * 512 + 256 + o] * (1.f / 128.f);
    float al1 = g1p[o] * rsqrtf(q1 - m1 * m1 + 1e-5f);
    float be1 = b1p[o] - m1 * al1;
    float m2 = ws[OFF_CS + (size_t)convR2 * 512 + o] * (1.f / 128.f);
    float q2 = ws[OFF_CS + (size_t)convR2 * 512 + 256 + o] * (1.f / 128.f);
    float al2 = g2p[o] * rsqrtf(q2 - m2 * m2 + 1e-5f);
    float be2 = b2p[o] - m2 * al2;
#pragma unroll
    for (int k = 0; k < 8; ++k) {
        edge_s[o * 9 + k] = egr[o * 8 + k];
        r1_s[o * 9 + k] = fmaxf(al1 * y1[o * 8 + k] + be1, 0.f);
        r2_s[o * 9 + k] = fmaxf(al2 * y2[o * 8 + k] + be2, 0.f);
    }
    __syncthreads();

    // a = softmax_l(edge^T r1)
    if (o < 64) {
        int k = o >> 3, l = o & 7;
        float s = 0.f;
        for (int i = 0; i < CC; ++i) s += edge_s[i * 9 + k] * r1_s[i * 9 + l];
        am[k * 9 + l] = s;
    }
    __syncthreads();
    if (o < 8) {
        float mx = -1e30f;
#pragma unroll
        for (int l = 0; l < 8; ++l) mx = fmaxf(mx, am[o * 9 + l]);
        float e[8], sm = 0.f;
#pragma unroll
        for (int l = 0; l < 8; ++l) { e[l] = expf(am[o * 9 + l] - mx); sm += e[l]; }
        float inv = 1.f / sm;
#pragma unroll
        for (int l = 0; l < 8; ++l) am[o * 9 + l] = e[l] * inv;
    }
    __syncthreads();

    // x0 = edge + a @ r2
#pragma unroll
    for (int k = 0; k < 8; ++k) {
        float mm = 0.f;
#pragma unroll
        for (int l = 0; l < 8; ++l) mm += am[k * 9 + l] * r2_s[o * 9 + l];
        x0[o * 9 + k] = edge_s[o * 9 + k] + mm;
    }
    __syncthreads();

    gcn_layer(gcn1, x0, x1, am, sup, o, false);
    gcn_layer(gcn2, x1, x0, am, sup, o, true);   // relu after second layer

    // ce = cw @ edge_final ; BN stat ingredients via s and G
    float ac[8];
#pragma unroll
    for (int k = 0; k < 8; ++k) ac[k] = 0.f;
    for (int i = 0; i < CC; ++i) {
        float w = cwT[(size_t)i * 256 + o];
#pragma unroll
        for (int k = 0; k < 8; ++k) ac[k] += w * x0[i * 9 + k];
    }
    float* ce = ws + OFF_CE + ((size_t)D * BB + b) * 2048;
    float smv = 0.f, sqv = 0.f;
#pragma unroll
    for (int k = 0; k < 8; ++k) {
        ce[o * 8 + k] = ac[k];
        smv += ac[k] * sS[k];
#pragma unroll
        for (int l = 0; l < 8; ++l) sqv += ac[k] * ac[l] * gS[k * 8 + l];
    }
    atomicAdd(&ws[OFF_MS + (size_t)D * 512 + o], smv);
    atomicAdd(&ws[OFF_MS + (size_t)D * 512 + 256 + o], sqv);
}

// ---------------- K6: out = gate*X + relu(BN(ce @ assign)) ----------------
// Pure write of out (no RMW): x recomputed from gate (stashed in out plane 0)
// and the original input X. 512 threads: tn = n within chunk, th = c-half.
__global__ __launch_bounds__(512) void k6_final(
    const float* __restrict__ rgb, const float* __restrict__ t,
    const float* __restrict__ t2rg, const float* __restrict__ t2rb,
    const float* __restrict__ r2tg, const float* __restrict__ r2tb,
    float* __restrict__ out, const float* __restrict__ ws)
{
    int chunk = blockIdx.x;         // 0..15
    int b = blockIdx.y, D = blockIdx.z;
    int tid = threadIdx.x;
    int tn = tid & 255, th = tid >> 8;
    int n = chunk * 256 + tn;

    const float* X = D ? t : rgb;
    float* obase = out + (((size_t)D * BB + b) * CC) * NN;

    // gate must be read by ALL threads before any thread overwrites plane 0
    float gt = obase[n];

    const float* assign_g = ws + OFF_ASSIGN + (((size_t)D * BB + b) * KK) * NN;
    float a0 = assign_g[0 * NN + n], a1 = assign_g[1 * NN + n];
    float a2 = assign_g[2 * NN + n], a3 = assign_g[3 * NN + n];
    float a4 = assign_g[4 * NN + n], a5 = assign_g[5 * NN + n];
    float a6 = assign_g[6 * NN + n], a7 = assign_g[7 * NN + n];

    __shared__ __align__(16) float ce_s[2048];
    __shared__ float al_s[256], be_s[256];
    const float* ce = ws + OFF_CE + ((size_t)D * BB + b) * 2048;
    for (int i = tid; i < 2048; i += 512) ce_s[i] = ce[i];
    if (tid < 256) {
        int o = tid;
        float m = ws[OFF_MS + (size_t)D * 512 + o] * (1.f / 65536.f);
        float q = ws[OFF_MS + (size_t)D * 512 + 256 + o] * (1.f / 65536.f);
        const float* g = D ? r2tg : t2rg;
        const float* bb = D ? r2tb : t2rb;
        float al = g[o] * rsqrtf(q - m * m + 1e-5f);
        al_s[o] = al;
        be_s[o] = bb[o] - m * al;
    }
    __syncthreads();

    const float* Xb = X + ((size_t)b * CC) * NN + n;
    const float4* ce4 = (const float4*)ce_s;
#pragma unroll 4
    for (int i = 0; i < 128; ++i) {
        int c = th * 128 + i;
        float4 ca = ce4[2 * c];
        float4 cb = ce4[2 * c + 1];
        float y = ca.x * a0 + ca.y * a1 + ca.z * a2 + ca.w * a3
                + cb.x * a4 + cb.y * a5 + cb.z * a6 + cb.w * a7;
        float v = fmaxf(al_s[c] * y + be_s[c], 0.f);
        obase[(size_t)c * NN + n] = gt * Xb[(size_t)c * NN] + v;
    }
}

extern "C" void kernel_launch(void* const* d_in, const int* in_sizes, int n_in,
                              void* d_out, int out_size, void* d_ws, size_t ws_size,
                              hipStream_t stream) {
    (void)in_sizes; (void)n_in; (void)out_size; (void)ws_size;
    const float* rgb    = (const float*)d_in[0];
    const float* t      = (const float*)d_in[1];
    const float* edger  = (const float*)d_in[2];
    const float* edget  = (const float*)d_in[3];
    const float* pred_w = (const float*)d_in[4];
    const float* pred_b = (const float*)d_in[5];
    const float* anch_r = (const float*)d_in[6];
    const float* sig_r  = (const float*)d_in[7];
    const float* anch_t = (const float*)d_in[8];
    const float* sig_t  = (const float*)d_in[9];
    const float* rc1w = (const float*)d_in[10];
    const float* rc1g = (const float*)d_in[11];
    const float* rc1b = (const float*)d_in[12];
    const float* rc2w = (const float*)d_in[13];
    const float* rc2g = (const float*)d_in[14];
    const float* rc2b = (const float*)d_in[15];
    const float* tc1w = (const float*)d_in[16];
    const float* tc1g = (const float*)d_in[17];
    const float* tc1b = (const float*)d_in[18];
    const float* tc2w = (const float*)d_in[19];
    const float* tc2g = (const float*)d_in[20];
    const float* tc2b = (const float*)d_in[21];
    const float* t2rcw = (const float*)d_in[22];
    const float* t2rcg = (const float*)d_in[23];
    const float* t2rcb = (const float*)d_in[24];
    const float* r2tcw = (const float*)d_in[25];
    const float* r2tcg = (const float*)d_in[26];
    const float* r2tcb = (const float*)d_in[27];
    const float* t2rg1 = (const float*)d_in[28];
    const float* t2rg2 = (const float*)d_in[29];
    const float* r2tg1 = (const float*)d_in[30];
    const float* r2tg2 = (const float*)d_in[31];

    float* out = (float*)d_out;
    float* ws = (float*)d_ws;

    hipMemsetAsync(ws, 0, ACC_FLOATS * sizeof(float), stream);
    k0_prep<<<1552, 256, 0, stream>>>(rc1w, rc2w, tc1w, tc2w, t2rcw, r2tcw,
                                      anch_r, sig_r, anch_t, sig_t, ws);
    k1_gate_assign<<<dim3(64, 16, 2), 256, 0, stream>>>(rgb, t, edger, edget,
                                                        pred_w, pred_b, out, ws);
    k2_nodes<<<32, 256, 0, stream>>>(anch_r, sig_r, anch_t, sig_t, ws);
    k3_conv<<<64, 256, 0, stream>>>(ws);
    k4_mutual<<<32, 256, 0, stream>>>(rc1g, rc1b, rc2g, rc2b, tc1g, tc1b, tc2g, tc2b,
                                      t2rg1, t2rg2, r2tg1, r2tg2, ws);
    k6_final<<<dim3(16, 16, 2), 512, 0, stream>>>(rgb, t, t2rcg, t2rcb, r2tcg, r2tcb,
                                                  out, ws);
}

// Round 2
// 591.692 us; speedup vs baseline: 1.0594x; 1.0594x over previous
//
#include <hip/hip_runtime.h>
#include <math.h>

#define BB 16
#define CC 256
#define NN 4096
#define KK 8

// ws layout (float offsets)
#define OFF_S      ((size_t)0)          // [2][16][8]
#define OFF_WX     ((size_t)256)        // [2][16][8][256]
#define OFF_G      ((size_t)65792)      // [2][16][64]
#define OFF_CS     ((size_t)67840)      // [4 conv][2][256]  (sum, sumsq)
#define OFF_MS     ((size_t)69888)      // [2 dir][2][256]
#define OFF_CK     ((size_t)70912)      // [2][8]  sum_c anchor^2 * inv_s2
#define ACC_FLOATS ((size_t)70928)
#define OFF_ASSIGN ((size_t)70928)      // [2][16][8][4096]
#define OFF_GRAPH  ((size_t)1119504)    // [2][16][2048]  (nodes layout k*256+c; [C][K] view = flat[c*8+k])
#define OFF_CLP    ((size_t)1185040)    // float2 [2][256][8]: per (c,k): (inv_s2, -2*anchor*inv_s2)
#define OFF_WT     ((size_t)1193232)    // [6][256][256] transposed conv weights
#define OFF_Y      ((size_t)1586448)    // [4 conv][16][256][8] raw conv outputs
#define OFF_CE     ((size_t)1717520)    // [2 dir][16][256][8]
#define WS_FLOATS  ((size_t)1783056)

// ---------------- K0: weight transposes + cluster params ----------------
__global__ __launch_bounds__(256) void k0_prep(
    const float* __restrict__ w0, const float* __restrict__ w1,
    const float* __restrict__ w2, const float* __restrict__ w3,
    const float* __restrict__ w4, const float* __restrict__ w5,
    const float* __restrict__ anch_r, const float* __restrict__ sig_r,
    const float* __restrict__ anch_t, const float* __restrict__ sig_t,
    float* __restrict__ ws)
{
    int bid = blockIdx.x, tid = threadIdx.x;
    if (bid < 1536) {
        int widx = bid >> 8;
        int e = ((bid & 255) << 8) + tid;     // 0..65535
        int o = e >> 8, i = e & 255;
        const float* W = widx == 0 ? w0 : widx == 1 ? w1 : widx == 2 ? w2 :
                         widx == 3 ? w3 : widx == 4 ? w4 : w5;
        ws[OFF_WT + (size_t)widx * 65536 + (size_t)i * 256 + o] = W[o * 256 + i];
    } else {
        int pid = ((bid - 1536) << 8) + tid;  // 0..4095
        int M = pid >> 11, j = pid & 2047;
        int k = j >> 8, c = j & 255;
        const float* sg = M ? sig_t : sig_r;
        const float* an = M ? anch_t : anch_r;
        float s = 1.f / (1.f + expf(-sg[j]));
        float is2 = 1.f / (s * s);
        float a = an[j];
        float2* c2 = (float2*)(ws + OFF_CLP);
        // interleaved [c][k] layout -> k1 stages 4x float4 per channel into LDS
        c2[(size_t)M * 2048 + (size_t)c * 8 + k] = make_float2(is2, -2.f * a * is2);
        // per-cluster constant term of the distance (k-dependent -> NOT softmax-invariant)
        atomicAdd(&ws[OFF_CK + (size_t)M * 8 + k], a * a * is2);
    }
}

// ---------------- KG: gate = sigmoid(pred_w . E + pred_b), row-major reads ----------------
// Each thread owns 2 consecutive n and sweeps all 256 channels: contiguous
// 512B/wave requests instead of k1's strided 256B columns. Gate stashed in
// out's channel-0 plane (k1 reads it; k6 reads then overwrites it).
__global__ __launch_bounds__(256) void kgate(
    const float* __restrict__ edger, const float* __restrict__ edget,
    const float* __restrict__ pred_w, const float* __restrict__ pred_b,
    float* __restrict__ out)
{
    int chunk = blockIdx.x;          // 0..7 (512 n each)
    int b = blockIdx.y, M = blockIdx.z;
    int n = chunk * 512 + threadIdx.x * 2;
    const float* E = M ? edget : edger;
    const float* Eb = E + ((size_t)b * CC) * NN + n;
    float ax = 0.f, ay = 0.f;
#pragma unroll 8
    for (int c = 0; c < CC; ++c) {
        float w = pred_w[c];
        float2 e = *(const float2*)(Eb + (size_t)c * NN);
        ax += w * e.x; ay += w * e.y;
    }
    float pb = pred_b[0];
    float2 g;
    g.x = 1.f / (1.f + expf(-(ax + pb)));
    g.y = 1.f / (1.f + expf(-(ay + pb)));
    *(float2*)(out + (((size_t)M * BB + b) * CC) * NN + n) = g;
}

// ---------------- K1: assign, wx/s/G accumulation ----------------
// Coefficients back in LDS (round-1 regression: in-loop global coeff loads
// serialized the X-load pipeline). Gate read from out plane 0 (kgate).
__global__ __launch_bounds__(256) void k1_assign(
    const float* __restrict__ rgb, const float* __restrict__ t,
    const float* __restrict__ out, float* __restrict__ ws)
{
    int tile = blockIdx.x;          // 0..63
    int b    = blockIdx.y;          // 0..15
    int M    = blockIdx.z;          // 0 rgb, 1 t
    int tid  = threadIdx.x;
    int tx = tid & 63, ty = tid >> 6;
    int n0 = tile * 64;

    const float* X = M ? t : rgb;

    __shared__ _Float16 xs[CC][66];
    __shared__ float4 pr4[1024];    // [256 c][4] : (is2,-2a*is2) pairs for k=0..7
    __shared__ float qp[KK][4][64];
    __shared__ float asg[KK][64];
    __shared__ float cks[KK];

    const float4* prg = (const float4*)(ws + OFF_CLP) + (size_t)M * 1024;
    for (int i = tid; i < 1024; i += 256) pr4[i] = prg[i];
    if (tid < KK) cks[tid] = ws[OFF_CK + (size_t)M * 8 + tid];

    // gate from kgate's stash (wave-coalesced 256B read, L2-warm)
    float gt = out[(((size_t)M * BB + b) * CC) * NN + n0 + tx];
    __syncthreads();

    // phase B: x = gate*input, stage to LDS, partial q
    const float* Xb = X + ((size_t)b * CC) * NN + n0 + tx;
    float qk[KK];
#pragma unroll
    for (int k = 0; k < KK; ++k) qk[k] = 0.f;
#pragma unroll 4
    for (int c = ty * 64; c < ty * 64 + 64; ++c) {
        float x = gt * Xb[(size_t)c * NN];
        xs[c][tx] = (_Float16)x;
        float xx = x * x;
        float4 p0 = pr4[c * 4 + 0];   // k=0,1 : (is2, -2a*is2)
        float4 p1 = pr4[c * 4 + 1];   // k=2,3
        float4 p2 = pr4[c * 4 + 2];   // k=4,5
        float4 p3 = pr4[c * 4 + 3];   // k=6,7
        qk[0] += xx * p0.x + x * p0.y;  qk[1] += xx * p0.z + x * p0.w;
        qk[2] += xx * p1.x + x * p1.y;  qk[3] += xx * p1.z + x * p1.w;
        qk[4] += xx * p2.x + x * p2.y;  qk[5] += xx * p2.z + x * p2.w;
        qk[6] += xx * p3.x + x * p3.y;  qk[7] += xx * p3.z + x * p3.w;
    }
#pragma unroll
    for (int k = 0; k < KK; ++k) qp[k][ty][tx] = qk[k];
    __syncthreads();

    // phase C: softmax over clusters (wave 0)
    float* assign_g = ws + OFF_ASSIGN + (((size_t)M * BB + b) * KK) * NN;
    if (tid < 64) {
        float q[KK], mx = -1e30f;
#pragma unroll
        for (int k = 0; k < KK; ++k) {
            q[k] = -0.5f * (qp[k][0][tx] + qp[k][1][tx] + qp[k][2][tx] + qp[k][3][tx] + cks[k]);
            mx = fmaxf(mx, q[k]);
        }
        float sm = 0.f;
#pragma unroll
        for (int k = 0; k < KK; ++k) { q[k] = expf(q[k] - mx); sm += q[k]; }
        float inv = 1.f / sm;
#pragma unroll
        for (int k = 0; k < KK; ++k) {
            float a = q[k] * inv;
            asg[k][tx] = a;
            assign_g[(size_t)k * NN + n0 + tx] = a;
        }
    }
    __syncthreads();

    // phase D: wx partial (matmul assign[8x64] @ x[64x256]) + s + G
    {
        int c = tid;
        float a0[KK];
#pragma unroll
        for (int k = 0; k < KK; ++k) a0[k] = 0.f;
#pragma unroll 4
        for (int j = 0; j < 64; ++j) {
            float xv = (float)xs[c][j];
#pragma unroll
            for (int k = 0; k < KK; ++k) a0[k] += asg[k][j] * xv;
        }
        float* wx_g = ws + OFF_WX + ((size_t)M * BB + b) * KK * CC;
#pragma unroll
        for (int k = 0; k < KK; ++k)
            atomicAdd(&wx_g[k * CC + c], a0[k]);
    }
    if (tid < 64) {
        int k1 = tid >> 3, k2 = tid & 7;
        float g = 0.f;
        for (int j = 0; j < 64; ++j) g += asg[k1][j] * asg[k2][j];
        atomicAdd(&ws[OFF_G + ((size_t)M * BB + b) * 64 + tid], g);
    } else if (tid < 72) {
        int k = tid - 64;
        float sv = 0.f;
        for (int j = 0; j < 64; ++j) sv += asg[k][j];
        atomicAdd(&ws[OFF_S + ((size_t)M * BB + b) * KK + k], sv);
    }
}

// ---------------- K2: nodes + double l2-normalize -> graph ----------------
__global__ __launch_bounds__(256) void k2_nodes(
    const float* __restrict__ anch_r, const float* __restrict__ sig_r,
    const float* __restrict__ anch_t, const float* __restrict__ sig_t,
    float* __restrict__ ws)
{
    int b = blockIdx.x & 15, M = blockIdx.x >> 4;
    int c = threadIdx.x;
    const float* an = M ? anch_t : anch_r;
    const float* sg = M ? sig_t : sig_r;
    const float* wx = ws + OFF_WX + ((size_t)M * BB + b) * KK * CC;
    const float* sp = ws + OFF_S + ((size_t)M * BB + b) * KK;
    float* gout = ws + OFF_GRAPH + ((size_t)M * BB + b) * 2048;

    __shared__ float nod[KK][CC];
    __shared__ float nrm[KK];
    __shared__ float gp[CC];
    __shared__ float gnrm;

    float node[KK];
#pragma unroll
    for (int k = 0; k < KK; ++k) {
        float s = sp[k];
        float sig = 1.f / (1.f + expf(-sg[k * CC + c]));
        float v = (wx[k * CC + c] - s * an[k * CC + c]) / sig / (s + 1e-9f);
        node[k] = v;
        nod[k][c] = v;
    }
    __syncthreads();
    if (c < KK) {
        float ss = 0.f;
        for (int i = 0; i < CC; ++i) ss += nod[c][i] * nod[c][i];
        nrm[c] = fmaxf(sqrtf(ss), 1e-12f);
    }
    __syncthreads();
    float gs = 0.f;
#pragma unroll
    for (int k = 0; k < KK; ++k) { node[k] /= nrm[k]; gs += node[k] * node[k]; }
    gp[c] = gs;
    __syncthreads();
    if (c == 0) {
        float ss = 0.f;
        for (int i = 0; i < CC; ++i) ss += gp[i];
        gnrm = fmaxf(sqrtf(ss), 1e-12f);
    }
    __syncthreads();
    float inv = 1.f / gnrm;
#pragma unroll
    for (int k = 0; k < KK; ++k)
        gout[k * CC + c] = node[k] * inv;   // nodes layout == flat; [C][K] view reads flat[c*8+k]
}

// ---------------- K3: four graph convs (raw y) + BN stats ----------------
__global__ __launch_bounds__(256) void k3_conv(float* __restrict__ ws)
{
    int conv = blockIdx.x >> 4, b = blockIdx.x & 15;
    int o = threadIdx.x;
    int M = conv >> 1;
    const float* gsrc = ws + OFF_GRAPH + ((size_t)M * BB + b) * 2048;
    const float* wt = ws + OFF_WT + (size_t)conv * 65536;
    __shared__ float gsh[2048];
    for (int i = o; i < 2048; i += 256) gsh[i] = gsrc[i];
    __syncthreads();
    float acc[KK];
#pragma unroll
    for (int k = 0; k < KK; ++k) acc[k] = 0.f;
    for (int i = 0; i < CC; ++i) {
        float w = wt[(size_t)i * 256 + o];
#pragma unroll
        for (int k = 0; k < KK; ++k) acc[k] += w * gsh[i * 8 + k];  // edge[i][k] = flat[i*8+k]
    }
    float* y = ws + OFF_Y + ((size_t)conv * BB + b) * 2048;
    float s1 = 0.f, s2 = 0.f;
#pragma unroll
    for (int k = 0; k < KK; ++k) { y[o * 8 + k] = acc[k]; s1 += acc[k]; s2 += acc[k] * acc[k]; }
    atomicAdd(&ws[OFF_CS + (size_t)conv * 512 + o], s1);
    atomicAdd(&ws[OFF_CS + (size_t)conv * 512 + 256 + o], s2);
}

// ---------------- K4: mutual correlation + cascade GCN + ce + final BN stats ----------------
__device__ __forceinline__ void gcn_layer(const float* __restrict__ Wg,
                                          float* xin, float* xout, float* am,
                                          float* sup, int o, bool do_relu)
{
    if (o < 64) {
        int k = o >> 3, l = o & 7;
        float s = 0.f;
        for (int i = 0; i < CC; ++i) s += xin[i * 9 + k] * xin[i * 9 + l];
        am[k * 9 + l] = s;
    }
    __syncthreads();
    if (o < 8) {
        float mx = -1e30f;
#pragma unroll
        for (int l = 0; l < 8; ++l) mx = fmaxf(mx, am[o * 9 + l]);
        float e[8], sm = 0.f;
#pragma unroll
        for (int l = 0; l < 8; ++l) { e[l] = expf(am[o * 9 + l] - mx); sm += e[l]; }
        float inv = 1.f / sm;
#pragma unroll
        for (int l = 0; l < 8; ++l) am[o * 9 + l] = e[l] * inv;
    }
    // sup[k][o] = sum_i xin[i][k] * Wg[i][o]   (independent of am)
    float sa[8];
#pragma unroll
    for (int k = 0; k < 8; ++k) sa[k] = 0.f;
    for (int i = 0; i < CC; ++i) {
        float w = Wg[(size_t)i * 256 + o];
#pragma unroll
        for (int k = 0; k < 8; ++k) sa[k] += xin[i * 9 + k] * w;
    }
#pragma unroll
    for (int k = 0; k < 8; ++k) sup[k * 256 + o] = sa[k];
    __syncthreads();
#pragma unroll
    for (int k = 0; k < 8; ++k) {
        float v = 0.f;
#pragma unroll
        for (int l = 0; l < 8; ++l) v += am[k * 9 + l] * sup[l * 256 + o];
        xout[o * 9 + k] = do_relu ? fmaxf(v, 0.f) : v;
    }
    __syncthreads();
}

__global__ __launch_bounds__(256) void k4_mutual(
    const float* __restrict__ rc1g, const float* __restrict__ rc1b,
    const float* __restrict__ rc2g, const float* __restrict__ rc2b,
    const float* __restrict__ tc1g, const float* __restrict__ tc1b,
    const float* __restrict__ tc2g, const float* __restrict__ tc2b,
    const float* __restrict__ t2rg1, const float* __restrict__ t2rg2,
    const float* __restrict__ r2tg1, const float* __restrict__ r2tg2,
    float* __restrict__ ws)
{
    int D = blockIdx.x >> 4, b = blockIdx.x & 15;
    int o = threadIdx.x;
    int M = D;                             // assign/graph modality of the receiving side
    int convR1 = D ? 0 : 2;                // r1 source conv
    int convR2 = D ? 1 : 3;
    const float* g1p = D ? rc1g : tc1g;  const float* b1p = D ? rc1b : tc1b;
    const float* g2p = D ? rc2g : tc2g;  const float* b2p = D ? rc2b : tc2b;
    const float* gcn1 = D ? r2tg1 : t2rg1;
    const float* gcn2 = D ? r2tg2 : t2rg2;
    const float* cwT = ws + OFF_WT + (size_t)(4 + D) * 65536;

    __shared__ float edge_s[CC * 9];
    __shared__ float r1_s[CC * 9];
    __shared__ float r2_s[CC * 9];
    __shared__ float x0[CC * 9];
    __shared__ float x1[CC * 9];
    __shared__ float sup[KK * CC];
    __shared__ float am[KK * 9];
    __shared__ float sS[KK];
    __shared__ float gS[64];

    if (o < 8)  sS[o] = ws[OFF_S + ((size_t)M * BB + b) * 8 + o];
    if (o < 64) gS[o] = ws[OFF_G + ((size_t)M * BB + b) * 64 + o];

    const float* egr = ws + OFF_GRAPH + ((size_t)M * BB + b) * 2048;
    const float* y1 = ws + OFF_Y + ((size_t)convR1 * BB + b) * 2048;
    const float* y2 = ws + OFF_Y + ((size_t)convR2 * BB + b) * 2048;
    float m1 = ws[OFF_CS + (size_t)convR1 * 512 + o] * (1.f / 128.f);
    float q1 = ws[OFF_CS + (size_t)convR1 * 512 + 256 + o] * (1.f / 128.f);
    float al1 = g1p[o] * rsqrtf(q1 - m1 * m1 + 1e-5f);
    float be1 = b1p[o] - m1 * al1;
    float m2 = ws[OFF_CS + (size_t)convR2 * 512 + o] * (1.f / 128.f);
    float q2 = ws[OFF_CS + (size_t)convR2 * 512 + 256 + o] * (1.f / 128.f);
    float al2 = g2p[o] * rsqrtf(q2 - m2 * m2 + 1e-5f);
    float be2 = b2p[o] - m2 * al2;
#pragma unroll
    for (int k = 0; k < 8; ++k) {
        edge_s[o * 9 + k] = egr[o * 8 + k];
        r1_s[o * 9 + k] = fmaxf(al1 * y1[o * 8 + k] + be1, 0.f);
        r2_s[o * 9 + k] = fmaxf(al2 * y2[o * 8 + k] + be2, 0.f);
    }
    __syncthreads();

    // a = softmax_l(edge^T r1)
    if (o < 64) {
        int k = o >> 3, l = o & 7;
        float s = 0.f;
        for (int i = 0; i < CC; ++i) s += edge_s[i * 9 + k] * r1_s[i * 9 + l];
        am[k * 9 + l] = s;
    }
    __syncthreads();
    if (o < 8) {
        float mx = -1e30f;
#pragma unroll
        for (int l = 0; l < 8; ++l) mx = fmaxf(mx, am[o * 9 + l]);
        float e[8], sm = 0.f;
#pragma unroll
        for (int l = 0; l < 8; ++l) { e[l] = expf(am[o * 9 + l] - mx); sm += e[l]; }
        float inv = 1.f / sm;
#pragma unroll
        for (int l = 0; l < 8; ++l) am[o * 9 + l] = e[l] * inv;
    }
    __syncthreads();

    // x0 = edge + a @ r2
#pragma unroll
    for (int k = 0; k < 8; ++k) {
        float mm = 0.f;
#pragma unroll
        for (int l = 0; l < 8; ++l) mm += am[k * 9 + l] * r2_s[o * 9 + l];
        x0[o * 9 + k] = edge_s[o * 9 + k] + mm;
    }
    __syncthreads();

    gcn_layer(gcn1, x0, x1, am, sup, o, false);
    gcn_layer(gcn2, x1, x0, am, sup, o, true);   // relu after second layer

    // ce = cw @ edge_final ; BN stat ingredients via s and G
    float ac[8];
#pragma unroll
    for (int k = 0; k < 8; ++k) ac[k] = 0.f;
    for (int i = 0; i < CC; ++i) {
        float w = cwT[(size_t)i * 256 + o];
#pragma unroll
        for (int k = 0; k < 8; ++k) ac[k] += w * x0[i * 9 + k];
    }
    float* ce = ws + OFF_CE + ((size_t)D * BB + b) * 2048;
    float smv = 0.f, sqv = 0.f;
#pragma unroll
    for (int k = 0; k < 8; ++k) {
        ce[o * 8 + k] = ac[k];
        smv += ac[k] * sS[k];
#pragma unroll
        for (int l = 0; l < 8; ++l) sqv += ac[k] * ac[l] * gS[k * 8 + l];
    }
    atomicAdd(&ws[OFF_MS + (size_t)D * 512 + o], smv);
    atomicAdd(&ws[OFF_MS + (size_t)D * 512 + 256 + o], sqv);
}

// ---------------- K6: out = gate*X + relu(BN(ce @ assign)), float2 vectorized ----------------
// 512 threads = 4 channel-quarters (th) x 128 n-lanes x float2.
// 512B contiguous requests for X read and out write; assign read once per n.
__global__ __launch_bounds__(512) void k6_final(
    const float* __restrict__ rgb, const float* __restrict__ t,
    const float* __restrict__ t2rg, const float* __restrict__ t2rb,
    const float* __restrict__ r2tg, const float* __restrict__ r2tb,
    float* __restrict__ out, const float* __restrict__ ws)
{
    int chunk = blockIdx.x;         // 0..15 (256 n each)
    int b = blockIdx.y, D = blockIdx.z;
    int tid = threadIdx.x;
    int ln = tid & 127;             // n-lane
    int th = tid >> 7;              // 0..3 channel quarter
    int n = chunk * 256 + ln * 2;

    const float* X = D ? t : rgb;
    float* obase = out + (((size_t)D * BB + b) * CC) * NN;

    // gate must be read by ALL threads before th=0 overwrites plane 0
    float2 gt2 = *(const float2*)(obase + n);

    const float* assign_g = ws + OFF_ASSIGN + (((size_t)D * BB + b) * KK) * NN;
    float2 a[KK];
#pragma unroll
    for (int k = 0; k < KK; ++k)
        a[k] = *(const float2*)(assign_g + (size_t)k * NN + n);

    __shared__ __align__(16) float4 ce_s[512];   // [256 c][2]
    __shared__ float al_s[256], be_s[256];
    const float4* ce = (const float4*)(ws + OFF_CE + ((size_t)D * BB + b) * 2048);
    ce_s[tid] = ce[tid];            // 512 float4 = exactly one per thread
    if (tid < 256) {
        int o = tid;
        float m = ws[OFF_MS + (size_t)D * 512 + o] * (1.f / 65536.f);
        float q = ws[OFF_MS + (size_t)D * 512 + 256 + o] * (1.f / 65536.f);
        const float* g = D ? r2tg : t2rg;
        const float* bb = D ? r2tb : t2rb;
        float al = g[o] * rsqrtf(q - m * m + 1e-5f);
        al_s[o] = al;
        be_s[o] = bb[o] - m * al;
    }
    __syncthreads();

    const float* Xb = X + ((size_t)b * CC) * NN + n;
#pragma unroll 4
    for (int i = 0; i < 64; ++i) {
        int c = th * 64 + i;
        float4 ca = ce_s[2 * c];
        float4 cb = ce_s[2 * c + 1];
        float2 xv = *(const float2*)(Xb + (size_t)c * NN);
        float y0 = ca.x * a[0].x + ca.y * a[1].x + ca.z * a[2].x + ca.w * a[3].x
                 + cb.x * a[4].x + cb.y * a[5].x + cb.z * a[6].x + cb.w * a[7].x;
        float y1 = ca.x * a[0].y + ca.y * a[1].y + ca.z * a[2].y + ca.w * a[3].y
                 + cb.x * a[4].y + cb.y * a[5].y + cb.z * a[6].y + cb.w * a[7].y;
        float al = al_s[c], be = be_s[c];
        float2 r;
        r.x = gt2.x * xv.x + fmaxf(al * y0 + be, 0.f);
        r.y = gt2.y * xv.y + fmaxf(al * y1 + be, 0.f);
        *(float2*)(obase + (size_t)c * NN + n) = r;
    }
}

extern "C" void kernel_launch(void* const* d_in, const int* in_sizes, int n_in,
                              void* d_out, int out_size, void* d_ws, size_t ws_size,
                              hipStream_t stream) {
    (void)in_sizes; (void)n_in; (void)out_size; (void)ws_size;
    const float* rgb    = (const float*)d_in[0];
    const float* t      = (const float*)d_in[1];
    const float* edger  = (const float*)d_in[2];
    const float* edget  = (const float*)d_in[3];
    const float* pred_w = (const float*)d_in[4];
    const float* pred_b = (const float*)d_in[5];
    const float* anch_r = (const float*)d_in[6];
    const float* sig_r  = (const float*)d_in[7];
    const float* anch_t = (const float*)d_in[8];
    const float* sig_t  = (const float*)d_in[9];
    const float* rc1w = (const float*)d_in[10];
    const float* rc1g = (const float*)d_in[11];
    const float* rc1b = (const float*)d_in[12];
    const float* rc2w = (const float*)d_in[13];
    const float* rc2g = (const float*)d_in[14];
    const float* rc2b = (const float*)d_in[15];
    const float* tc1w = (const float*)d_in[16];
    const float* tc1g = (const float*)d_in[17];
    const float* tc1b = (const float*)d_in[18];
    const float* tc2w = (const float*)d_in[19];
    const float* tc2g = (const float*)d_in[20];
    const float* tc2b = (const float*)d_in[21];
    const float* t2rcw = (const float*)d_in[22];
    const float* t2rcg = (const float*)d_in[23];
    const float* t2rcb = (const float*)d_in[24];
    const float* r2tcw = (const float*)d_in[25];
    const float* r2tcg = (const float*)d_in[26];
    const float* r2tcb = (const float*)d_in[27];
    const float* t2rg1 = (const float*)d_in[28];
    const float* t2rg2 = (const float*)d_in[29];
    const float* r2tg1 = (const float*)d_in[30];
    const float* r2tg2 = (const float*)d_in[31];

    float* out = (float*)d_out;
    float* ws = (float*)d_ws;

    hipMemsetAsync(ws, 0, ACC_FLOATS * sizeof(float), stream);
    k0_prep<<<1552, 256, 0, stream>>>(rc1w, rc2w, tc1w, tc2w, t2rcw, r2tcw,
                                      anch_r, sig_r, anch_t, sig_t, ws);
    kgate<<<dim3(8, 16, 2), 256, 0, stream>>>(edger, edget, pred_w, pred_b, out);
    k1_assign<<<dim3(64, 16, 2), 256, 0, stream>>>(rgb, t, out, ws);
    k2_nodes<<<32, 256, 0, stream>>>(anch_r, sig_r, anch_t, sig_t, ws);
    k3_conv<<<64, 256, 0, stream>>>(ws);
    k4_mutual<<<32, 256, 0, stream>>>(rc1g, rc1b, rc2g, rc2b, tc1g, tc1b, tc2g, tc2b,
                                      t2rg1, t2rg2, r2tg1, r2tg2, ws);
    k6_final<<<dim3(16, 16, 2), 512, 0, stream>>>(rgb, t, t2rcg, t2rcb, r2tcg, r2tcb,
                                                  out, ws);
}